// Round 6
// baseline (136.921 us; speedup 1.0000x reference)
//
#include <hip/hip_runtime.h>

// Problem constants (match reference)
constexpr int   B_ = 8;
constexpr int   T_ = 100;
constexpr int   NPAIRS = B_ * T_;      // 800
constexpr int   N_ = 100000;
constexpr float MARGIN_ = 0.1f;
constexpr float THRESHOLD_ = 0.5f;
constexpr float BIG_ = 1000000000.0f;

// Workspace layout (bytes) — only ~20 KB used now
constexpr size_t PAIRS_OFF  = 0;                      // float4[800]: (rx,ry,rz,0)
constexpr size_t BOUNDS_OFF = 16384;                  // float[48]: l[8][3], u[8][3]
constexpr size_t KEYS_OFF   = BOUNDS_OFF + 256;       // uint[800] orderable min-keys
constexpr size_t CNT_OFF    = KEYS_OFF + NPAIRS * 4;  // uint: finished-block counter

// fast hardware sqrt: single v_sqrt_f32
__device__ __forceinline__ float fsqrt(float x) { return __builtin_amdgcn_sqrtf(x); }

// Map float -> uint such that uint order == float order (handles negatives).
__device__ __forceinline__ unsigned fkey(float f) {
    unsigned u = __float_as_uint(f);
    return (u & 0x80000000u) ? ~u : (u | 0x80000000u);
}

// K1: pairs (retrajs), per-b AABB bounds, init min-keys + block counter. 1 block x 1024.
__global__ void k_prep(const float* __restrict__ outputs,
                       const float* __restrict__ c2ws,
                       const float* __restrict__ ss,
                       char* ws) {
    __shared__ float re_s[NPAIRS * 3];
    int tid = threadIdx.x;
    float4*   pairs  = (float4*)(ws + PAIRS_OFF);
    float*    bounds = (float*)(ws + BOUNDS_OFF);
    unsigned* keys   = (unsigned*)(ws + KEYS_OFF);
    unsigned* cnt    = (unsigned*)(ws + CNT_OFF);

    if (tid == 0) *cnt = 0;  // re-arm last-block counter every call (ws re-poisoned)

    if (tid < NPAIRS) {
        int b = tid / T_;
        float s = ss[b];
        const float* o = outputs + tid * 3;
        float o0 = o[0], o1 = o[1], o2 = o[2];
        const float* c = c2ws + b * 16;
        float re[3];
#pragma unroll
        for (int e = 0; e < 3; e++) {
            re[e] = (o0 * c[e * 4 + 0] + o1 * c[e * 4 + 1] + o2 * c[e * 4 + 2]) * s + c[e * 4 + 3];
            re_s[tid * 3 + e] = re[e];
        }
        pairs[tid] = make_float4(re[0], re[1], re[2], 0.f);
        keys[tid]  = fkey(BIG_);  // re-init keys every call
    }

    __syncthreads();
    if (tid < 24) {
        int b = tid / 3, e = tid - b * 3;
        float mx = -3.4e38f, mn = 3.4e38f;
        for (int t = 0; t < T_; t++) {
            float v = re_s[(b * T_ + t) * 3 + e];
            mx = fmaxf(mx, v);
            mn = fminf(mn, v);
        }
        float thres = THRESHOLD_ * ss[0];  // reference uses scene_scales[0] for all b
        bounds[b * 3 + e]      = mn - thres;  // lvals
        bounds[24 + b * 3 + e] = mx + thres;  // uvals
    }
}

// K2 (fused main): each block owns PER=98 splats. Staging phase loads means/
// scales DIRECTLY from inputs (each splat used by exactly one block — no global
// precompute round-trip), computes msr_eff[b] = inside_b ? maxrad+MARGIN : -BIG.
// Main loop: 3 pairs per thread as NAMED SCALARS; wave-0 tail for pairs 768-799
// (minimizes total issue cycles; other resident blocks keep the SIMDs fed).
// Last block (device-scope counter) reduces keys -> out (saves k_final launch).
constexpr int PER = 98;
constexpr int NBLK = (N_ + PER - 1) / PER;  // 1021

__global__ __launch_bounds__(256) void k_main(const float* __restrict__ means,
                                              const float* __restrict__ scales,
                                              const char* __restrict__ wsc, char* ws,
                                              float* __restrict__ out) {
    __shared__ float4 pm_s[PER];
    __shared__ float  msr_s[PER * 8];
    __shared__ int    isLast;
    __shared__ float  wsum[4];
    int tid = threadIdx.x;
    const float4* pairs  = (const float4*)(wsc + PAIRS_OFF);
    const float*  bounds = (const float*)(wsc + BOUNDS_OFF);
    unsigned* keys = (unsigned*)(ws + KEYS_OFF);
    unsigned* cnt  = (unsigned*)(ws + CNT_OFF);

    int base = blockIdx.x * PER;
    int cntn = min(PER, N_ - base);

    // stage splats straight from inputs; fold AABB mask into msr_eff
    if (tid < cntn) {
        int n = base + tid;
        float mx = means[(size_t)n * 3 + 0];
        float my = means[(size_t)n * 3 + 1];
        float mz = means[(size_t)n * 3 + 2];
        float msr = fmaxf(fmaxf(scales[(size_t)n * 3 + 0], scales[(size_t)n * 3 + 1]),
                          scales[(size_t)n * 3 + 2]) + MARGIN_;
        pm_s[tid] = make_float4(mx, my, mz, 0.f);
#pragma unroll
        for (int b = 0; b < 8; b++) {
            bool in = (mx >= bounds[b * 3 + 0]) & (mx <= bounds[24 + b * 3 + 0]) &
                      (my >= bounds[b * 3 + 1]) & (my <= bounds[24 + b * 3 + 1]) &
                      (mz >= bounds[b * 3 + 2]) & (mz <= bounds[24 + b * 3 + 2]);
            msr_s[tid * 8 + b] = in ? msr : -BIG_;
        }
    }

    // per-thread pairs as named scalars
    int p0 = tid, p1 = tid + 256, p2 = tid + 512;
    float4 q0 = pairs[p0];
    float4 q1 = pairs[p1];
    float4 q2 = pairs[p2];
    int b0 = p0 / T_, b1 = p1 / T_, b2 = p2 / T_;

    __syncthreads();

    float mn0 = BIG_, mn1 = BIG_, mn2 = BIG_;
    const float*  mp = msr_s;
    const float4* sp = pm_s;
    for (int i = 0; i < cntn; i++) {
        float4 m = sp[i];
        float e0 = mp[b0], e1 = mp[b1], e2 = mp[b2];
        mp += 8;
        float dx, dy, dz, d2;
        dx = q0.x - m.x; dy = q0.y - m.y; dz = q0.z - m.z;
        d2 = fmaf(dz, dz, fmaf(dy, dy, dx * dx));
        mn0 = fminf(mn0, fsqrt(d2) - e0);
        dx = q1.x - m.x; dy = q1.y - m.y; dz = q1.z - m.z;
        d2 = fmaf(dz, dz, fmaf(dy, dy, dx * dx));
        mn1 = fminf(mn1, fsqrt(d2) - e1);
        dx = q2.x - m.x; dy = q2.y - m.y; dz = q2.z - m.z;
        d2 = fmaf(dz, dz, fmaf(dy, dy, dx * dx));
        mn2 = fminf(mn2, fsqrt(d2) - e2);
    }
    atomicMin(&keys[p0], fkey(mn0));
    atomicMin(&keys[p1], fkey(mn1));
    atomicMin(&keys[p2], fkey(mn2));

    // tail: pairs 768..799 on lanes 0..31 of wave 0 (other waves skip via execz;
    // resident sibling blocks keep those SIMDs issuing)
    if (tid < 32) {
        int p3 = 768 + tid;
        float4 q3 = pairs[p3];
        int b3 = p3 / T_;
        float mn3 = BIG_;
        const float* mp3 = msr_s;
        for (int i = 0; i < cntn; i++) {
            float4 m = pm_s[i];
            float e3 = mp3[b3];
            mp3 += 8;
            float dx = q3.x - m.x, dy = q3.y - m.y, dz = q3.z - m.z;
            float d2 = fmaf(dz, dz, fmaf(dy, dy, dx * dx));
            mn3 = fminf(mn3, fsqrt(d2) - e3);
        }
        atomicMin(&keys[p3], fkey(mn3));
    }

    // last-block final reduction (replaces k_final launch)
    __threadfence();  // release: make our atomicMin results visible
    if (tid == 0) {
        unsigned prev = atomicAdd(cnt, 1u);
        isLast = (prev == (unsigned)(NBLK - 1));
    }
    __syncthreads();
    if (isLast) {
        __threadfence();  // acquire: see all blocks' atomicMin results
        float acc = 0.f;
        for (int p = tid; p < NPAIRS; p += 256) {
            unsigned k = __hip_atomic_load(&keys[p], __ATOMIC_RELAXED, __HIP_MEMORY_SCOPE_AGENT);
            unsigned u = (k & 0x80000000u) ? (k ^ 0x80000000u) : ~k;
            float f = __uint_as_float(u);
            acc += fmaxf(0.f, -f);
        }
#pragma unroll
        for (int off = 32; off; off >>= 1) acc += __shfl_down(acc, off, 64);
        if ((tid & 63) == 0) wsum[tid >> 6] = acc;
        __syncthreads();
        if (tid == 0) out[0] = (wsum[0] + wsum[1] + wsum[2] + wsum[3]) / (float)(B_ * T_);
    }
}

extern "C" void kernel_launch(void* const* d_in, const int* in_sizes, int n_in,
                              void* d_out, int out_size, void* d_ws, size_t ws_size,
                              hipStream_t stream) {
    const float* outputs = (const float*)d_in[0];   // (B,T,3)
    const float* c2ws    = (const float*)d_in[1];   // (B,4,4)
    const float* ss      = (const float*)d_in[2];   // (B,)
    const float* means   = (const float*)d_in[3];   // (N,3)
    const float* scales  = (const float*)d_in[4];   // (N,3)
    float* out = (float*)d_out;
    char*  ws  = (char*)d_ws;

    hipLaunchKernelGGL(k_prep, dim3(1), dim3(1024), 0, stream, outputs, c2ws, ss, ws);
    hipLaunchKernelGGL(k_main, dim3(NBLK), dim3(256), 0, stream,
                       means, scales, (const char*)ws, ws, out);
}